// Round 3
// baseline (1679.575 us; speedup 1.0000x reference)
//
#include <hip/hip_runtime.h>
#include <stdint.h>

#define TOKENS 8192
#define OUT_F  16384
#define IN_F   4096

typedef short bf16x8  __attribute__((ext_vector_type(8)));
typedef float f32x4   __attribute__((ext_vector_type(4)));
typedef float f32x16  __attribute__((ext_vector_type(16)));

__device__ __forceinline__ unsigned short bf16_rne(float f) {
    union { float f; unsigned int u; } v; v.f = f;
    unsigned int u = v.u;
    u += 0x7fffu + ((u >> 16) & 1u);   // round-to-nearest-even (finite inputs)
    return (unsigned short)(u >> 16);
}

__device__ __forceinline__ unsigned int pack_bf16x2(float a, float b) {
    return (unsigned int)bf16_rne(a) | ((unsigned int)bf16_rne(b) << 16);
}

// async global->LDS DMA, 16B/lane. LDS dst is wave-uniform base + lane*16.
__device__ __forceinline__ void async_cp16(const void* gptr, void* ldsptr) {
    __builtin_amdgcn_global_load_lds(
        (const __attribute__((address_space(1))) unsigned int*)gptr,
        (__attribute__((address_space(3))) unsigned int*)ldsptr,
        16, 0, 0);
}

// ---------------- pre-pass 1: x fp32 -> bf16 ----------------
__global__ __launch_bounds__(256) void cvt_input_kernel(
    const float* __restrict__ in, unsigned short* __restrict__ out, int n8)
{
    int i = blockIdx.x * 256 + threadIdx.x;
    if (i >= n8) return;
    size_t base = (size_t)i * 8;
    float4 a = *(const float4*)(in + base);
    float4 b = *(const float4*)(in + base + 4);
    uint4 p;
    p.x = pack_bf16x2(a.x, a.y);  p.y = pack_bf16x2(a.z, a.w);
    p.z = pack_bf16x2(b.x, b.y);  p.w = pack_bf16x2(b.z, b.w);
    *(uint4*)(out + base) = p;
}

// ---------------- pre-pass 2: idx -> bf16(LUT[idx]) ----------------
__global__ __launch_bounds__(256) void dequant_kernel(
    const int* __restrict__ idx, const float* __restrict__ lut,
    unsigned short* __restrict__ out, int n8)
{
    __shared__ float slut[256];
    slut[threadIdx.x] = lut[threadIdx.x];
    __syncthreads();
    int i = blockIdx.x * 256 + threadIdx.x;
    if (i >= n8) return;
    size_t base = (size_t)i * 8;
    int4 i0 = *(const int4*)(idx + base);
    int4 i1 = *(const int4*)(idx + base + 4);
    uint4 p;
    p.x = pack_bf16x2(slut[i0.x], slut[i0.y]);
    p.y = pack_bf16x2(slut[i0.z], slut[i0.w]);
    p.z = pack_bf16x2(slut[i1.x], slut[i1.y]);
    p.w = pack_bf16x2(slut[i1.z], slut[i1.w]);
    *(uint4*)(out + base) = p;
}

// ============ 256x256 GEMM, 32x32x16 MFMA, k-step read pipeline ============
// C[M,N] = A[M,K] * B[N,K]^T + bias.  BM=BN=256, BK=64, 8 waves (2M x 4N),
// LDS 128 KiB = 2 buffers x (A[2x128x64] + B[2x128x64]) bf16.
// Per buffer byte map: A0=0, A1=16384, B0=32768, B1=49152.  buf1 base = 65536.
// Per wave per tile: 4 k-steps (K=16 each); phase kk reads fragments for
// kk+1 (6 ds_read_b128) then MFMAs kk (8 x mfma_32x32x16) -> compiler emits
// counted lgkmcnt, reads overlap previous k-step's MFMAs.
// 2 barriers/tile: Br1 (lgkmcnt(0): all RB reads done -> A(t+2) may write RB),
// Br2 (vmcnt(4) gate: only A(t+2)'s 4 DMA in flight -> tile t+1 certified).
// Staging per tile per wave (8 DMA): B(t+1)->WB early-tile, A(t+2)->RB after Br1.
// LDS swizzle (T2): phys = logical ^ (((logical>>7)&7)<<4) — involution,
// applied as pre-swizzled global SOURCE (linear global_load_lds dest) and as
// XOR on the ds_read column offset.
__global__ __launch_bounds__(512, 2) void palett_gemm256(
    const unsigned short* __restrict__ A,   // [TOKENS][IN_F] bf16
    const unsigned short* __restrict__ B,   // [OUT_F][IN_F] bf16
    const float* __restrict__ bias,
    float* __restrict__ out)
{
    __shared__ __align__(16) char sm[131072];

    const int t    = threadIdx.x;
    const int w    = t >> 6;       // wave 0..7
    const int l    = t & 63;
    const int l31  = l & 31;
    const int hi   = l >> 5;       // 0..1
    const int wr   = w >> 2;       // wave M row   (0..1) -> 128 rows
    const int wc   = w & 3;        // wave N col   (0..3) -> 64 cols

    // T1: XCD-aware bijective block swizzle (nwg=2048, 2048%8==0)
    const int orig = blockIdx.y * gridDim.x + blockIdx.x;   // 0..2047
    const int swzb = (orig & 7) * 256 + (orig >> 3);
    const int n0   = (swzb & 63) << 8;
    const int m0   = (swzb >> 6) << 8;

    // staging source (pre-swizzled): lane covers row srow (+8 for 2nd load),
    // 16B chunk at swizzled column ((l&7)^(l>>3))*8 elems.
    const int srow = w * 16 + (l >> 3);              // 0..127 within half
    const int scol = ((l & 7) ^ (l >> 3)) << 3;      // elems
    const unsigned short* pA = A + (size_t)(m0 + srow) * IN_F + scol;
    const unsigned short* pB = B + (size_t)(n0 + srow) * IN_F + scol;

    // ds_read addressing: fragment (frag, kk) at LDS row (frag*32 + l31),
    // byte col (kk*32 + hi*16) ^ ((row&7)<<4); row&7 == l&7.
    const int arow  = l31 * 128;
    const int bcol  = ((hi ^ (l & 7)) << 4);         // hi*16 XOR cswz (disjoint-bit sum == xor)
    const int abase = wr * 16384;                            // this wave's A half
    const int bbase = 32768 + (wc >> 1) * 16384 + (wc & 1) * 8192; // B half + sub

    f32x16 acc[4][2] = {};
    bf16x8 fA[2][4], fB[2][2];

#define STAGE(P, HOFF, LOFF, KOFF) do {                                          \
    async_cp16((P) + (size_t)(HOFF) * IN_F + (KOFF), sm + (LOFF) + w * 2048);    \
    async_cp16((P) + (size_t)((HOFF) + 8) * IN_F + (KOFF),                       \
               sm + (LOFF) + w * 2048 + 1024);                                   \
} while (0)

#define READ_K(S_, RB_, KK_) do {                                                \
    _Pragma("unroll")                                                            \
    for (int m_ = 0; m_ < 4; ++m_)                                               \
        fA[S_][m_] = *(const bf16x8*)(sm + (RB_) + abase + m_ * 4096 + arow      \
                                      + (((KK_) * 32) ^ bcol));                  \
    _Pragma("unroll")                                                            \
    for (int n_ = 0; n_ < 2; ++n_)                                               \
        fB[S_][n_] = *(const bf16x8*)(sm + (RB_) + bbase + n_ * 4096 + arow      \
                                      + (((KK_) * 32) ^ bcol));                  \
} while (0)

#define MFMA_K(S_) do {                                                          \
    __builtin_amdgcn_s_setprio(1);                                               \
    _Pragma("unroll")                                                            \
    for (int m_ = 0; m_ < 4; ++m_) {                                             \
        _Pragma("unroll")                                                        \
        for (int n_ = 0; n_ < 2; ++n_)                                           \
            acc[m_][n_] = __builtin_amdgcn_mfma_f32_32x32x16_bf16(               \
                fA[S_][m_], fB[S_][n_], acc[m_][n_], 0, 0, 0);                   \
    }                                                                            \
    __builtin_amdgcn_s_setprio(0);                                               \
} while (0)

// KB_ = elem k-offset of tile t+1 (B staging), KA_ = k-offset of tile t+2 (A staging)
#define TILE(RB_, WB_, KB_, KA_) do {                                            \
    READ_K(0, RB_, 0);                                                           \
    STAGE(pB, 0,   (WB_) + 32768, KB_);                                          \
    READ_K(1, RB_, 1);                                                           \
    MFMA_K(0);                           /* kk=0; waits own f0 only */           \
    STAGE(pB, 128, (WB_) + 49152, KB_);                                          \
    READ_K(0, RB_, 2);                                                           \
    MFMA_K(1);                           /* kk=1 */                              \
    READ_K(1, RB_, 3);                                                           \
    MFMA_K(0);                           /* kk=2 */                              \
    asm volatile("s_waitcnt lgkmcnt(0)" ::: "memory");  /* all RB reads done */  \
    asm volatile("s_barrier" ::: "memory");             /* Br1: RB writable */   \
    STAGE(pA, 0,   (RB_) + 0,     KA_);                                          \
    STAGE(pA, 128, (RB_) + 16384, KA_);                                          \
    MFMA_K(1);                           /* kk=3 */                              \
    asm volatile("s_waitcnt vmcnt(4)" ::: "memory");    /* t+1 fully landed */   \
    asm volatile("s_barrier" ::: "memory");             /* Br2: gate */          \
} while (0)

    // prologue: tile0 (all 4 half-tiles) -> buf0, A of tile1 -> buf1
    STAGE(pA, 0,   0,             0);
    STAGE(pA, 128, 16384,         0);
    STAGE(pB, 0,   32768,         0);
    STAGE(pB, 128, 49152,         0);
    STAGE(pA, 0,   65536 + 0,     64);
    STAGE(pA, 128, 65536 + 16384, 64);
    asm volatile("s_waitcnt vmcnt(4)" ::: "memory");  // tile0 landed, A(1) in flight
    asm volatile("s_barrier" ::: "memory");

#pragma unroll 1
    for (int it = 0; it < 32; ++it) {
        const int tt  = 2 * it;
        const int kB0 = ((tt + 1) & 63) * 64;   // B of tile tt+1
        const int kA0 = ((tt + 2) & 63) * 64;   // A of tile tt+2
        const int kB1 = ((tt + 2) & 63) * 64;   // B of tile tt+2
        const int kA1 = ((tt + 3) & 63) * 64;   // A of tile tt+3
        TILE(0,     65536, kB0, kA0);
        TILE(65536, 0,     kB1, kA1);
    }
    asm volatile("s_waitcnt vmcnt(0)" ::: "memory"); // drain dangling prefetch

#undef TILE
#undef MFMA_K
#undef READ_K
#undef STAGE

    // epilogue: 32x32 C/D layout col = l&31, row = (reg&3) + 8*(reg>>2) + 4*hi
    float bj[2];
#pragma unroll
    for (int nj = 0; nj < 2; ++nj) bj[nj] = bias[n0 + wc * 64 + nj * 32 + l31];

#pragma unroll
    for (int mi = 0; mi < 4; ++mi) {
        const int mrow = m0 + wr * 128 + mi * 32 + hi * 4;
#pragma unroll
        for (int nj = 0; nj < 2; ++nj) {
            const int n = n0 + wc * 64 + nj * 32 + l31;
#pragma unroll
            for (int g = 0; g < 4; ++g) {
#pragma unroll
                for (int v = 0; v < 4; ++v) {
                    out[(size_t)(mrow + g * 8 + v) * OUT_F + n] =
                        acc[mi][nj][g * 4 + v] + bj[nj];
                }
            }
        }
    }
}

// ---------------- fused fallback (only if workspace too small) ----------------
__global__ __launch_bounds__(256) void palett_gemm_fused(
    const float* __restrict__ Af,             // [M][K] fp32
    const int* __restrict__ Widx,             // [N][K] int32
    const float* __restrict__ lut,
    const float* __restrict__ bias,
    float* __restrict__ out)
{
    __shared__ __align__(16) unsigned short smA[128 * 32];
    __shared__ __align__(16) unsigned short smB[128 * 32];
    __shared__ float slut[256];

    const int t    = threadIdx.x;
    const int w    = t >> 6;
    const int l    = t & 63;
    const int quad = l >> 4;
    const int r16  = l & 15;
    const int wr   = w >> 1;
    const int wc   = w & 1;

    const int m0 = blockIdx.y * 128;
    const int n0 = blockIdx.x * 128;

    const int g0  = t * 8;
    const int row = g0 >> 5;
    const int col = g0 & 31;

    char* const smA_c = (char*)smA;
    char* const smB_c = (char*)smB;

    slut[t] = lut[t];
    __syncthreads();

    uint32_t aoff[4], boff[4];
#pragma unroll
    for (int i = 0; i < 4; ++i) {
        aoff[i] = (uint32_t)(((wr * 64 + i * 16 + r16) * 32 + quad * 8) * 2);
        boff[i] = (uint32_t)(((wc * 64 + i * 16 + r16) * 32 + quad * 8) * 2);
    }

    f32x4 acc[4][4] = {};

    const float* af0 = Af + (size_t)(m0 + row) * IN_F + col;
    const float* af1 = Af + (size_t)(m0 + row + 64) * IN_F + col;
    const int*   wi0 = Widx + (size_t)(n0 + row) * IN_F + col;
    const int*   wi1 = Widx + (size_t)(n0 + row + 64) * IN_F + col;

    for (int k0 = 0; k0 < IN_F; k0 += 32) {
        float4 x0 = *(const float4*)(af0 + k0);
        float4 x1 = *(const float4*)(af0 + k0 + 4);
        uint4 p;
        p.x = pack_bf16x2(x0.x, x0.y); p.y = pack_bf16x2(x0.z, x0.w);
        p.z = pack_bf16x2(x1.x, x1.y); p.w = pack_bf16x2(x1.z, x1.w);
        *(uint4*)(smA_c + t * 16) = p;
        x0 = *(const float4*)(af1 + k0);
        x1 = *(const float4*)(af1 + k0 + 4);
        p.x = pack_bf16x2(x0.x, x0.y); p.y = pack_bf16x2(x0.z, x0.w);
        p.z = pack_bf16x2(x1.x, x1.y); p.w = pack_bf16x2(x1.z, x1.w);
        *(uint4*)(smA_c + 4096 + t * 16) = p;

        int4 j0 = *(const int4*)(wi0 + k0);
        int4 j1 = *(const int4*)(wi0 + k0 + 4);
        p.x = pack_bf16x2(slut[j0.x], slut[j0.y]);
        p.y = pack_bf16x2(slut[j0.z], slut[j0.w]);
        p.z = pack_bf16x2(slut[j1.x], slut[j1.y]);
        p.w = pack_bf16x2(slut[j1.z], slut[j1.w]);
        *(uint4*)(smB_c + t * 16) = p;
        j0 = *(const int4*)(wi1 + k0);
        j1 = *(const int4*)(wi1 + k0 + 4);
        p.x = pack_bf16x2(slut[j0.x], slut[j0.y]);
        p.y = pack_bf16x2(slut[j0.z], slut[j0.w]);
        p.z = pack_bf16x2(slut[j1.x], slut[j1.y]);
        p.w = pack_bf16x2(slut[j1.z], slut[j1.w]);
        *(uint4*)(smB_c + 4096 + t * 16) = p;
        __syncthreads();

        bf16x8 afr[4], bfr[4];
#pragma unroll
        for (int i = 0; i < 4; ++i) afr[i] = *(const bf16x8*)(smA_c + aoff[i]);
#pragma unroll
        for (int j = 0; j < 4; ++j) bfr[j] = *(const bf16x8*)(smB_c + boff[j]);
#pragma unroll
        for (int i = 0; i < 4; ++i)
#pragma unroll
            for (int j = 0; j < 4; ++j)
                acc[i][j] = __builtin_amdgcn_mfma_f32_16x16x32_bf16(
                    afr[i], bfr[j], acc[i][j], 0, 0, 0);
        __syncthreads();
    }

    float bj[4];
#pragma unroll
    for (int j = 0; j < 4; ++j) bj[j] = bias[n0 + wc * 64 + j * 16 + r16];

#pragma unroll
    for (int i = 0; i < 4; ++i) {
        const int mbase = m0 + wr * 64 + i * 16 + quad * 4;
#pragma unroll
        for (int j = 0; j < 4; ++j) {
            const int n = n0 + wc * 64 + j * 16 + r16;
#pragma unroll
            for (int v = 0; v < 4; ++v) {
                out[(size_t)(mbase + v) * OUT_F + n] = acc[i][j][v] + bj[j];
            }
        }
    }
}

extern "C" void kernel_launch(void* const* d_in, const int* in_sizes, int n_in,
                              void* d_out, int out_size, void* d_ws, size_t ws_size,
                              hipStream_t stream) {
    const float* input = (const float*)d_in[0];   // [8192][4096] fp32
    const int*   widx  = (const int*)d_in[1];     // [16384][4096] int32
    const float* lut   = (const float*)d_in[2];   // [256] fp32
    const float* bias  = (const float*)d_in[3];   // [16384] fp32
    float* out = (float*)d_out;                   // [8192][16384] fp32

    const size_t aBytes = (size_t)TOKENS * IN_F * sizeof(unsigned short); //  64 MB
    const size_t bBytes = (size_t)OUT_F  * IN_F * sizeof(unsigned short); // 128 MB

    if (ws_size >= aBytes + bBytes) {
        unsigned short* wsA = (unsigned short*)d_ws;
        unsigned short* wsB = (unsigned short*)((char*)d_ws + aBytes);
        const int nA8 = (TOKENS * IN_F) / 8;
        const int nB8 = (OUT_F  * IN_F) / 8;
        cvt_input_kernel<<<(nA8 + 255) / 256, 256, 0, stream>>>(input, wsA, nA8);
        dequant_kernel<<<(nB8 + 255) / 256, 256, 0, stream>>>(widx, lut, wsB, nB8);
        dim3 grid2(OUT_F / 256, TOKENS / 256);    // (64, 32) = 2048 blocks
        palett_gemm256<<<grid2, 512, 0, stream>>>(wsA, wsB, bias, out);
    } else {
        dim3 grid(OUT_F / 128, TOKENS / 128);
        palett_gemm_fused<<<grid, 256, 0, stream>>>(input, widx, lut, bias, out);
    }
}

// Round 4
// 1629.821 us; speedup vs baseline: 1.0305x; 1.0305x over previous
//
#include <hip/hip_runtime.h>
#include <stdint.h>

#define TOKENS 8192
#define OUT_F  16384
#define IN_F   4096

typedef short bf16x8 __attribute__((ext_vector_type(8)));
typedef float f32x4  __attribute__((ext_vector_type(4)));

__device__ __forceinline__ unsigned short bf16_rne(float f) {
    union { float f; unsigned int u; } v; v.f = f;
    unsigned int u = v.u;
    u += 0x7fffu + ((u >> 16) & 1u);   // round-to-nearest-even (finite inputs)
    return (unsigned short)(u >> 16);
}

__device__ __forceinline__ unsigned int pack_bf16x2(float a, float b) {
    return (unsigned int)bf16_rne(a) | ((unsigned int)bf16_rne(b) << 16);
}

// async global->LDS DMA, 16B/lane. LDS dst is wave-uniform base + lane*16.
__device__ __forceinline__ void async_cp16(const void* gptr, void* ldsptr) {
    __builtin_amdgcn_global_load_lds(
        (const __attribute__((address_space(1))) unsigned int*)gptr,
        (__attribute__((address_space(3))) unsigned int*)ldsptr,
        16, 0, 0);
}

// ---------------- pre-pass 1: x fp32 -> bf16 ----------------
__global__ __launch_bounds__(256) void cvt_input_kernel(
    const float* __restrict__ in, unsigned short* __restrict__ out, int n8)
{
    int i = blockIdx.x * 256 + threadIdx.x;
    if (i >= n8) return;
    size_t base = (size_t)i * 8;
    float4 a = *(const float4*)(in + base);
    float4 b = *(const float4*)(in + base + 4);
    uint4 p;
    p.x = pack_bf16x2(a.x, a.y);  p.y = pack_bf16x2(a.z, a.w);
    p.z = pack_bf16x2(b.x, b.y);  p.w = pack_bf16x2(b.z, b.w);
    *(uint4*)(out + base) = p;
}

// ---------------- pre-pass 2: idx -> bf16(LUT[idx]) ----------------
__global__ __launch_bounds__(256) void dequant_kernel(
    const int* __restrict__ idx, const float* __restrict__ lut,
    unsigned short* __restrict__ out, int n8)
{
    __shared__ float slut[256];
    slut[threadIdx.x] = lut[threadIdx.x];
    __syncthreads();
    int i = blockIdx.x * 256 + threadIdx.x;
    if (i >= n8) return;
    size_t base = (size_t)i * 8;
    int4 i0 = *(const int4*)(idx + base);
    int4 i1 = *(const int4*)(idx + base + 4);
    uint4 p;
    p.x = pack_bf16x2(slut[i0.x], slut[i0.y]);
    p.y = pack_bf16x2(slut[i0.z], slut[i0.w]);
    p.z = pack_bf16x2(slut[i1.x], slut[i1.y]);
    p.w = pack_bf16x2(slut[i1.z], slut[i1.w]);
    *(uint4*)(out + base) = p;
}

// ============ 256x256 GEMM, m201-faithful 4-phase schedule ============
// C[M,N] = A[M,K] * B[N,K]^T + bias.  BM=BN=256, BK=64, 8 waves (2M x 4N),
// 16x16x32 MFMA, LDS 128 KiB = 2 buffers x (A[2x128x64] + B[2x128x64]) bf16.
// Buffer byte map: A0=0, A1=16384, B0=32768, B1=49152.  buf1 base = 65536.
// Per tile: 4 phases, each = { ds_reads + 1 half-tile stage -> s_barrier ->
// lgkmcnt(0) (reads fly ACROSS the barrier) -> 16-MFMA cluster -> s_barrier }.
//   ph1: read A0-3(k0,k1)+B0-1 (12); stage B-lo(t+1);  MFMA m0-3 x n0-1
//   ph2: read B2-3 (4);             stage B-hi(t+1);  MFMA m0-3 x n2-3
//   ph3: read A4-7 (8, reuse regs);                   MFMA m4-7 x n0-1
//   ph4: stage A-lo,A-hi(t+2)->RB (safe: ph3 trailing barrier certifies all
//        RB reads consumed);                          MFMA m4-7 x n2-3;
//        vmcnt(4) gate (leaves only A(t+2) in flight -> tile t+1 certified)
// LDS swizzle (T2): phys = logical ^ (((logical>>7)&7)<<4) — involution,
// applied as pre-swizzled global SOURCE (linear global_load_lds dest) and as
// XOR on the ds_read column offset.  This read pattern measured 0 bank
// conflicts (round 2).
__global__ __launch_bounds__(512, 2) void palett_gemm256(
    const unsigned short* __restrict__ A,   // [TOKENS][IN_F] bf16
    const unsigned short* __restrict__ B,   // [OUT_F][IN_F] bf16
    const float* __restrict__ bias,
    float* __restrict__ out)
{
    __shared__ __align__(16) char sm[131072];

    const int t    = threadIdx.x;
    const int w    = t >> 6;       // wave 0..7
    const int l    = t & 63;
    const int quad = l >> 4;
    const int r16  = l & 15;
    const int wr   = w >> 2;       // wave M row   (0..1) -> 128 rows
    const int wc   = w & 3;        // wave N col   (0..3) -> 64 cols

    // T1: XCD-aware bijective block swizzle (nwg=2048, 2048%8==0)
    const int orig = blockIdx.y * gridDim.x + blockIdx.x;   // 0..2047
    const int swzb = (orig & 7) * 256 + (orig >> 3);
    const int n0   = (swzb & 63) << 8;
    const int m0   = (swzb >> 6) << 8;

    // staging source (pre-swizzled): lane covers row srow (+8 for 2nd load),
    // 16B chunk at swizzled column ((l&7)^(l>>3))*8 elems.
    const int srow = w * 16 + (l >> 3);              // 0..127 within half
    const int scol = ((l & 7) ^ (l >> 3)) << 3;      // elems
    const unsigned short* pA = A + (size_t)(m0 + srow) * IN_F + scol;
    const unsigned short* pB = B + (size_t)(n0 + srow) * IN_F + scol;

    // ds_read byte-offset components (XOR-swizzled columns) — round-2 verified
    const int cswz  = (r16 & 7) << 4;
    const int col0  = (quad * 16) ^ cswz;            // kk=0
    const int col1  = (64 + quad * 16) ^ cswz;       // kk=1
    const int arow  = r16 * 128;
    const int abase = wr * 16384;                            // this wave's A half
    const int bbase = 32768 + (wc >> 1) * 16384 + (wc & 1) * 8192; // B half + sub

    f32x4  acc[8][4] = {};
    bf16x8 fA[4][2], fB[4][2];

#define BAR()   asm volatile("s_barrier" ::: "memory")
#define LGKM0() do { asm volatile("s_waitcnt lgkmcnt(0)" ::: "memory");          \
                     __builtin_amdgcn_sched_barrier(0); } while (0)

#define STAGE(P, HOFF, LOFF, KOFF) do {                                          \
    async_cp16((P) + (size_t)(HOFF) * IN_F + (KOFF), sm + (LOFF) + w * 2048);    \
    async_cp16((P) + (size_t)((HOFF) + 8) * IN_F + (KOFF),                       \
               sm + (LOFF) + w * 2048 + 1024);                                   \
} while (0)

// read A frag group G (4 frags, both k-halves) into fA
#define READ_A4(G, RB_) do {                                                     \
    _Pragma("unroll")                                                            \
    for (int i_ = 0; i_ < 4; ++i_) {                                             \
        fA[i_][0] = *(const bf16x8*)(sm + (RB_) + abase + ((G) + i_) * 2048      \
                                     + arow + col0);                             \
        fA[i_][1] = *(const bf16x8*)(sm + (RB_) + abase + ((G) + i_) * 2048      \
                                     + arow + col1);                             \
    }                                                                            \
} while (0)

// read B frags J,J+1 (both k-halves) into fB[J..J+1]
#define READ_B2(J, RB_) do {                                                     \
    _Pragma("unroll")                                                            \
    for (int j_ = 0; j_ < 2; ++j_) {                                             \
        fB[(J) + j_][0] = *(const bf16x8*)(sm + (RB_) + bbase                    \
                                           + ((J) + j_) * 2048 + arow + col0);   \
        fB[(J) + j_][1] = *(const bf16x8*)(sm + (RB_) + bbase                    \
                                           + ((J) + j_) * 2048 + arow + col1);   \
    }                                                                            \
} while (0)

// 16-MFMA cluster: m-frag base MB (0 or 4, fA holds that group), n-frags NH*2..+1
#define MFMA16(MB, NH) do {                                                      \
    __builtin_amdgcn_s_setprio(1);                                               \
    _Pragma("unroll")                                                            \
    for (int i_ = 0; i_ < 4; ++i_) {                                             \
        _Pragma("unroll")                                                        \
        for (int j_ = 0; j_ < 2; ++j_) {                                         \
            acc[(MB)+i_][(NH)*2+j_] = __builtin_amdgcn_mfma_f32_16x16x32_bf16(   \
                fA[i_][0], fB[(NH)*2+j_][0], acc[(MB)+i_][(NH)*2+j_], 0, 0, 0);  \
            acc[(MB)+i_][(NH)*2+j_] = __builtin_amdgcn_mfma_f32_16x16x32_bf16(   \
                fA[i_][1], fB[(NH)*2+j_][1], acc[(MB)+i_][(NH)*2+j_], 0, 0, 0);  \
        }                                                                        \
    }                                                                            \
    __builtin_amdgcn_s_setprio(0);                                               \
} while (0)

// KB_ = elem k-offset of tile t+1 (B staging), KA_ = k-offset of tile t+2 (A staging)
#define TILE(RB_, WB_, KB_, KA_) do {                                            \
    /* ph1 */                                                                    \
    READ_A4(0, RB_);                                                             \
    READ_B2(0, RB_);                                                             \
    STAGE(pB, 0, (WB_) + 32768, KB_);                                            \
    BAR();  LGKM0();                                                             \
    MFMA16(0, 0);                                                                \
    BAR();                                                                       \
    /* ph2 */                                                                    \
    READ_B2(2, RB_);                                                             \
    STAGE(pB, 128, (WB_) + 49152, KB_);                                          \
    BAR();  LGKM0();                                                             \
    MFMA16(0, 1);                                                                \
    BAR();                                                                       \
    /* ph3 */                                                                    \
    READ_A4(4, RB_);                                                             \
    BAR();  LGKM0();                                                             \
    MFMA16(4, 0);                                                                \
    BAR();   /* certifies: all waves' RB reads consumed -> RB writable */        \
    /* ph4 */                                                                    \
    STAGE(pA, 0,   (RB_) + 0,     KA_);                                          \
    STAGE(pA, 128, (RB_) + 16384, KA_);                                          \
    BAR();                                                                       \
    MFMA16(4, 1);                                                                \
    asm volatile("s_waitcnt vmcnt(4)" ::: "memory");   /* tile t+1 landed */     \
    BAR();                                                                       \
} while (0)

    // prologue: tile0 (all 4 half-tiles) -> buf0, A of tile1 -> buf1
    STAGE(pA, 0,   0,             0);
    STAGE(pA, 128, 16384,         0);
    STAGE(pB, 0,   32768,         0);
    STAGE(pB, 128, 49152,         0);
    STAGE(pA, 0,   65536 + 0,     64);
    STAGE(pA, 128, 65536 + 16384, 64);
    asm volatile("s_waitcnt vmcnt(4)" ::: "memory");  // tile0 landed, A(1) in flight
    BAR();

#pragma unroll 1
    for (int it = 0; it < 32; ++it) {
        const int tt  = 2 * it;
        const int kB0 = ((tt + 1) & 63) * 64;   // B of tile tt+1
        const int kA0 = ((tt + 2) & 63) * 64;   // A of tile tt+2
        const int kB1 = ((tt + 2) & 63) * 64;   // B of tile tt+2
        const int kA1 = ((tt + 3) & 63) * 64;   // A of tile tt+3
        TILE(0,     65536, kB0, kA0);
        TILE(65536, 0,     kB1, kA1);
    }
    asm volatile("s_waitcnt vmcnt(0)" ::: "memory"); // drain dangling prefetch

#undef TILE
#undef MFMA16
#undef READ_B2
#undef READ_A4
#undef STAGE
#undef LGKM0
#undef BAR

    // epilogue: C/D layout row = quad*4 + v, col = r16  (round-2 verified)
    float bj[4];
#pragma unroll
    for (int j = 0; j < 4; ++j) bj[j] = bias[n0 + wc * 64 + j * 16 + r16];

#pragma unroll
    for (int mf = 0; mf < 8; ++mf) {
        const int mrow = m0 + wr * 128 + mf * 16 + quad * 4;
#pragma unroll
        for (int nf = 0; nf < 4; ++nf) {
            const int n = n0 + wc * 64 + nf * 16 + r16;
#pragma unroll
            for (int v = 0; v < 4; ++v)
                out[(size_t)(mrow + v) * OUT_F + n] = acc[mf][nf][v] + bj[nf];
        }
    }
}

// ---------------- fused fallback (only if workspace too small) ----------------
__global__ __launch_bounds__(256) void palett_gemm_fused(
    const float* __restrict__ Af,             // [M][K] fp32
    const int* __restrict__ Widx,             // [N][K] int32
    const float* __restrict__ lut,
    const float* __restrict__ bias,
    float* __restrict__ out)
{
    __shared__ __align__(16) unsigned short smA[128 * 32];
    __shared__ __align__(16) unsigned short smB[128 * 32];
    __shared__ float slut[256];

    const int t    = threadIdx.x;
    const int w    = t >> 6;
    const int l    = t & 63;
    const int quad = l >> 4;
    const int r16  = l & 15;
    const int wr   = w >> 1;
    const int wc   = w & 1;

    const int m0 = blockIdx.y * 128;
    const int n0 = blockIdx.x * 128;

    const int g0  = t * 8;
    const int row = g0 >> 5;
    const int col = g0 & 31;

    char* const smA_c = (char*)smA;
    char* const smB_c = (char*)smB;

    slut[t] = lut[t];
    __syncthreads();

    uint32_t aoff[4], boff[4];
#pragma unroll
    for (int i = 0; i < 4; ++i) {
        aoff[i] = (uint32_t)(((wr * 64 + i * 16 + r16) * 32 + quad * 8) * 2);
        boff[i] = (uint32_t)(((wc * 64 + i * 16 + r16) * 32 + quad * 8) * 2);
    }

    f32x4 acc[4][4] = {};

    const float* af0 = Af + (size_t)(m0 + row) * IN_F + col;
    const float* af1 = Af + (size_t)(m0 + row + 64) * IN_F + col;
    const int*   wi0 = Widx + (size_t)(n0 + row) * IN_F + col;
    const int*   wi1 = Widx + (size_t)(n0 + row + 64) * IN_F + col;

    for (int k0 = 0; k0 < IN_F; k0 += 32) {
        float4 x0 = *(const float4*)(af0 + k0);
        float4 x1 = *(const float4*)(af0 + k0 + 4);
        uint4 p;
        p.x = pack_bf16x2(x0.x, x0.y); p.y = pack_bf16x2(x0.z, x0.w);
        p.z = pack_bf16x2(x1.x, x1.y); p.w = pack_bf16x2(x1.z, x1.w);
        *(uint4*)(smA_c + t * 16) = p;
        x0 = *(const float4*)(af1 + k0);
        x1 = *(const float4*)(af1 + k0 + 4);
        p.x = pack_bf16x2(x0.x, x0.y); p.y = pack_bf16x2(x0.z, x0.w);
        p.z = pack_bf16x2(x1.x, x1.y); p.w = pack_bf16x2(x1.z, x1.w);
        *(uint4*)(smA_c + 4096 + t * 16) = p;

        int4 j0 = *(const int4*)(wi0 + k0);
        int4 j1 = *(const int4*)(wi0 + k0 + 4);
        p.x = pack_bf16x2(slut[j0.x], slut[j0.y]);
        p.y = pack_bf16x2(slut[j0.z], slut[j0.w]);
        p.z = pack_bf16x2(slut[j1.x], slut[j1.y]);
        p.w = pack_bf16x2(slut[j1.z], slut[j1.w]);
        *(uint4*)(smB_c + t * 16) = p;
        j0 = *(const int4*)(wi1 + k0);
        j1 = *(const int4*)(wi1 + k0 + 4);
        p.x = pack_bf16x2(slut[j0.x], slut[j0.y]);
        p.y = pack_bf16x2(slut[j0.z], slut[j0.w]);
        p.z = pack_bf16x2(slut[j1.x], slut[j1.y]);
        p.w = pack_bf16x2(slut[j1.z], slut[j1.w]);
        *(uint4*)(smB_c + 4096 + t * 16) = p;
        __syncthreads();

        bf16x8 afr[4], bfr[4];
#pragma unroll
        for (int i = 0; i < 4; ++i) afr[i] = *(const bf16x8*)(smA_c + aoff[i]);
#pragma unroll
        for (int j = 0; j < 4; ++j) bfr[j] = *(const bf16x8*)(smB_c + boff[j]);
#pragma unroll
        for (int i = 0; i < 4; ++i)
#pragma unroll
            for (int j = 0; j < 4; ++j)
                acc[i][j] = __builtin_amdgcn_mfma_f32_16x16x32_bf16(
                    afr[i], bfr[j], acc[i][j], 0, 0, 0);
        __syncthreads();
    }

    float bj[4];
#pragma unroll
    for (int j = 0; j < 4; ++j) bj[j] = bias[n0 + wc * 64 + j * 16 + r16];

#pragma unroll
    for (int i = 0; i < 4; ++i) {
        const int mbase = m0 + wr * 64 + i * 16 + quad * 4;
#pragma unroll
        for (int j = 0; j < 4; ++j) {
            const int n = n0 + wc * 64 + j * 16 + r16;
#pragma unroll
            for (int v = 0; v < 4; ++v) {
                out[(size_t)(mbase + v) * OUT_F + n] = acc[i][j][v] + bj[j];
            }
        }
    }
}

extern "C" void kernel_launch(void* const* d_in, const int* in_sizes, int n_in,
                              void* d_out, int out_size, void* d_ws, size_t ws_size,
                              hipStream_t stream) {
    const float* input = (const float*)d_in[0];   // [8192][4096] fp32
    const int*   widx  = (const int*)d_in[1];     // [16384][4096] int32
    const float* lut   = (const float*)d_in[2];   // [256] fp32
    const float* bias  = (const float*)d_in[3];   // [16384] fp32
    float* out = (float*)d_out;                   // [8192][16384] fp32

    const size_t aBytes = (size_t)TOKENS * IN_F * sizeof(unsigned short); //  64 MB
    const size_t bBytes = (size_t)OUT_F  * IN_F * sizeof(unsigned short); // 128 MB

    if (ws_size >= aBytes + bBytes) {
        unsigned short* wsA = (unsigned short*)d_ws;
        unsigned short* wsB = (unsigned short*)((char*)d_ws + aBytes);
        const int nA8 = (TOKENS * IN_F) / 8;
        const int nB8 = (OUT_F  * IN_F) / 8;
        cvt_input_kernel<<<(nA8 + 255) / 256, 256, 0, stream>>>(input, wsA, nA8);
        dequant_kernel<<<(nB8 + 255) / 256, 256, 0, stream>>>(widx, lut, wsB, nB8);
        dim3 grid2(OUT_F / 256, TOKENS / 256);    // (64, 32) = 2048 blocks
        palett_gemm256<<<grid2, 512, 0, stream>>>(wsA, wsB, bias, out);
    } else {
        dim3 grid(OUT_F / 128, TOKENS / 128);
        palett_gemm_fused<<<grid, 256, 0, stream>>>(input, widx, lut, bias, out);
    }
}